// Round 1
// baseline (256.424 us; speedup 1.0000x reference)
//
#include <hip/hip_runtime.h>

#define NN 1024
#define FF 64
#define CC 4
#define EE 32768
#define HH 256

// ---------------------------------------------------------------------------
// A: agg[n][c][f] += x[src][f] * w   (edge-weighted scatter aggregation)
// layout agg[n*256 + c*64 + f] so the node-MLP input vector is contiguous.
__global__ __launch_bounds__(256)
void k_agg_scatter(const float* __restrict__ x, const int* __restrict__ ei,
                   const float* __restrict__ ew, float* __restrict__ agg)
{
    unsigned t = blockIdx.x * 256u + threadIdx.x;   // t < C*E*F = 2^23
    unsigned f = t & 63u;
    unsigned e = (t >> 6) & (EE - 1u);
    unsigned c = t >> 21;
    int src = ei[c * 2 * EE + e];
    int dst = ei[c * 2 * EE + EE + e];
    float w = ew[c * EE + e];
    atomicAdd(&agg[dst * (CC * FF) + c * FF + f], x[src * FF + f] * w);
}

// ---------------------------------------------------------------------------
// C: adense[i][j][c] += w   (dense adjacency, c fastest so a float4 per pair)
__global__ __launch_bounds__(256)
void k_adj_scatter(const int* __restrict__ ei, const float* __restrict__ ew,
                   float* __restrict__ adense)
{
    unsigned t = blockIdx.x * 256u + threadIdx.x;   // t < C*E = 131072
    unsigned e = t & (EE - 1u);
    unsigned c = t >> 15;
    int i = ei[c * 2 * EE + e];
    int j = ei[c * 2 * EE + EE + e];
    float w = ew[c * EE + e];
    atomicAdd(&adense[(i * NN + j) * CC + c], w);
}

// ---------------------------------------------------------------------------
// B1: hid[n][h] = relu(bn1[h] + sum_k (agg[n][k] + (1+eps)x[n][k%64]) * Wn1[k][h])
// 4 nodes per block to amortize Wn1 row reads.
__global__ __launch_bounds__(256)
void k_node_mlp1(const float* __restrict__ agg, const float* __restrict__ x,
                 const float* __restrict__ Wn1, const float* __restrict__ bn1,
                 const float* __restrict__ epsp, float* __restrict__ hid)
{
    __shared__ float hval[4][256];
    const int tid = threadIdx.x;
    const int n0 = blockIdx.x * 4;
    const float ope = 1.0f + epsp[0];
#pragma unroll
    for (int nn = 0; nn < 4; ++nn)
        hval[nn][tid] = agg[(n0 + nn) * 256 + tid] + ope * x[(n0 + nn) * 64 + (tid & 63)];
    __syncthreads();
    float a0 = bn1[tid], a1 = a0, a2 = a0, a3 = a0;
    for (int k = 0; k < 256; ++k) {
        float w = Wn1[k * 256 + tid];
        a0 += hval[0][k] * w;
        a1 += hval[1][k] * w;
        a2 += hval[2][k] * w;
        a3 += hval[3][k] * w;
    }
    hid[(n0 + 0) * 256 + tid] = fmaxf(a0, 0.f);
    hid[(n0 + 1) * 256 + tid] = fmaxf(a1, 0.f);
    hid[(n0 + 2) * 256 + tid] = fmaxf(a2, 0.f);
    hid[(n0 + 3) * 256 + tid] = fmaxf(a3, 0.f);
}

// ---------------------------------------------------------------------------
// B2: xn[n][f] = bn2[f] + hid[n][:] @ Wn2[:,f]
__global__ __launch_bounds__(256)
void k_node_mlp2(const float* __restrict__ hid, const float* __restrict__ Wn2,
                 const float* __restrict__ bn2, float* __restrict__ xn)
{
    __shared__ float hl[4][256];
    const int tid = threadIdx.x;
    const int n0 = blockIdx.x * 4;
#pragma unroll
    for (int r = 0; r < 4; ++r) hl[r][tid] = hid[(n0 + r) * 256 + tid];
    __syncthreads();
    const int nn = tid >> 6, f = tid & 63;
    float acc = bn2[f];
    for (int k = 0; k < 256; ++k)
        acc += hl[nn][k] * Wn2[k * 64 + f];
    xn[(n0 + nn) * 64 + f] = acc;
}

// ---------------------------------------------------------------------------
// PQ: P[n][h] = be1[h] + xn[n][:] @ We1[4:68, h]   (x_i contribution + bias)
//     Q[n][h] =          xn[n][:] @ We1[68:132, h] (x_j contribution)
__global__ __launch_bounds__(256)
void k_pq(const float* __restrict__ xn, const float* __restrict__ We1,
          const float* __restrict__ be1, float* __restrict__ P, float* __restrict__ Q)
{
    __shared__ float xl[4][64];
    const int tid = threadIdx.x;
    const int n0 = blockIdx.x * 4;
    xl[tid >> 6][tid & 63] = xn[n0 * 64 + tid];
    __syncthreads();
    float p0 = be1[tid], p1 = p0, p2 = p0, p3 = p0;
    float q0 = 0.f, q1 = 0.f, q2 = 0.f, q3 = 0.f;
    for (int f = 0; f < 64; ++f) {
        float wp = We1[(4 + f) * 256 + tid];
        float wq = We1[(68 + f) * 256 + tid];
        p0 += xl[0][f] * wp;  q0 += xl[0][f] * wq;
        p1 += xl[1][f] * wp;  q1 += xl[1][f] * wq;
        p2 += xl[2][f] * wp;  q2 += xl[2][f] * wq;
        p3 += xl[3][f] * wp;  q3 += xl[3][f] * wq;
    }
    P[(n0 + 0) * 256 + tid] = p0;  Q[(n0 + 0) * 256 + tid] = q0;
    P[(n0 + 1) * 256 + tid] = p1;  Q[(n0 + 1) * 256 + tid] = q1;
    P[(n0 + 2) * 256 + tid] = p2;  Q[(n0 + 2) * 256 + tid] = q2;
    P[(n0 + 3) * 256 + tid] = p3;  Q[(n0 + 3) * 256 + tid] = q3;
}

// ---------------------------------------------------------------------------
// D: out[i][j][o] = be2[o] + sum_h relu(P[i][h] + Q[j][h] + sum_c a[i][j][c]*We1[c][h]) * We2[h][o]
// 64x64 pair tile per block, 256 threads, 4x4 pairs per thread.
// P/Q staged in LDS as float4 with XOR bank swizzle (quad ^ ((row>>2)&7)).
__global__ __launch_bounds__(256, 1)
void k_edge_mlp(const float* __restrict__ P, const float* __restrict__ Q,
                const float* __restrict__ adense, const float* __restrict__ We1,
                const float* __restrict__ We2, const float* __restrict__ be2,
                float* __restrict__ out)
{
    __shared__ float4 Pl[64 * 64];   // [row][quad^swz], 64 KB
    __shared__ float4 Ql[64 * 64];   // 64 KB
    __shared__ float4 W2l[256];      // We2 row h -> float4 of 4 outputs
    __shared__ float4 W1l[4 * 64];   // We1[c][4q..4q+3]

    const int tid = threadIdx.x;
    const int iBase = blockIdx.y * 64;
    const int jBase = blockIdx.x * 64;

    for (int t = tid; t < 64 * 64; t += 256) {
        int row = t >> 6, q = t & 63;
        int ph = q ^ ((row >> 2) & 7);
        Pl[row * 64 + ph] = *(const float4*)(P + (iBase + row) * 256 + q * 4);
        Ql[row * 64 + ph] = *(const float4*)(Q + (jBase + row) * 256 + q * 4);
    }
    {
        int c = tid >> 6, q = tid & 63;
        W2l[tid] = *(const float4*)(We2 + tid * 4);
        W1l[tid] = *(const float4*)(We1 + c * 256 + q * 4);
    }
    __syncthreads();

    const int tx = tid & 15, ty = tid >> 4;
    const int ps = ty & 7, qs = tx & 7;

    float4 a[4][4];
#pragma unroll
    for (int ii = 0; ii < 4; ++ii)
#pragma unroll
        for (int jj = 0; jj < 4; ++jj)
            a[ii][jj] = *(const float4*)(adense +
                ((size_t)(iBase + ty * 4 + ii) * NN + (jBase + tx * 4 + jj)) * 4);

    float4 acc[4][4];
#pragma unroll
    for (int ii = 0; ii < 4; ++ii)
#pragma unroll
        for (int jj = 0; jj < 4; ++jj)
            acc[ii][jj] = make_float4(0.f, 0.f, 0.f, 0.f);

    for (int q = 0; q < 64; ++q) {
        float4 p[4], qv[4], w2[4], w1[4];
#pragma unroll
        for (int r = 0; r < 4; ++r) p[r]  = Pl[(ty * 4 + r) * 64 + (q ^ ps)];
#pragma unroll
        for (int r = 0; r < 4; ++r) qv[r] = Ql[(tx * 4 + r) * 64 + (q ^ qs)];
#pragma unroll
        for (int k = 0; k < 4; ++k) w2[k] = W2l[q * 4 + k];
#pragma unroll
        for (int c = 0; c < 4; ++c) w1[c] = W1l[c * 64 + q];

#pragma unroll
        for (int ii = 0; ii < 4; ++ii) {
#pragma unroll
            for (int jj = 0; jj < 4; ++jj) {
                const float4 av = a[ii][jj];
                float s0 = av.x * w1[0].x + av.y * w1[1].x + av.z * w1[2].x + av.w * w1[3].x;
                float s1 = av.x * w1[0].y + av.y * w1[1].y + av.z * w1[2].y + av.w * w1[3].y;
                float s2 = av.x * w1[0].z + av.y * w1[1].z + av.z * w1[2].z + av.w * w1[3].z;
                float s3 = av.x * w1[0].w + av.y * w1[1].w + av.z * w1[2].w + av.w * w1[3].w;
                float v0 = fmaxf(p[ii].x + qv[jj].x + s0, 0.f);
                float v1 = fmaxf(p[ii].y + qv[jj].y + s1, 0.f);
                float v2 = fmaxf(p[ii].z + qv[jj].z + s2, 0.f);
                float v3 = fmaxf(p[ii].w + qv[jj].w + s3, 0.f);
                acc[ii][jj].x += v0 * w2[0].x + v1 * w2[1].x + v2 * w2[2].x + v3 * w2[3].x;
                acc[ii][jj].y += v0 * w2[0].y + v1 * w2[1].y + v2 * w2[2].y + v3 * w2[3].y;
                acc[ii][jj].z += v0 * w2[0].z + v1 * w2[1].z + v2 * w2[2].z + v3 * w2[3].z;
                acc[ii][jj].w += v0 * w2[0].w + v1 * w2[1].w + v2 * w2[2].w + v3 * w2[3].w;
            }
        }
    }

    const float4 b2 = *(const float4*)be2;
#pragma unroll
    for (int ii = 0; ii < 4; ++ii) {
#pragma unroll
        for (int jj = 0; jj < 4; ++jj) {
            float4 o = acc[ii][jj];
            o.x += b2.x; o.y += b2.y; o.z += b2.z; o.w += b2.w;
            *(float4*)(out + ((size_t)(iBase + ty * 4 + ii) * NN + (jBase + tx * 4 + jj)) * 4) = o;
        }
    }
}

// ---------------------------------------------------------------------------
extern "C" void kernel_launch(void* const* d_in, const int* in_sizes, int n_in,
                              void* d_out, int out_size, void* d_ws, size_t ws_size,
                              hipStream_t stream)
{
    (void)in_sizes; (void)n_in; (void)out_size; (void)ws_size;
    const float* x   = (const float*)d_in[0];
    const int*   ei  = (const int*)d_in[1];
    const float* ew  = (const float*)d_in[2];
    const float* Wn1 = (const float*)d_in[3];
    const float* bn1 = (const float*)d_in[4];
    const float* Wn2 = (const float*)d_in[5];
    const float* bn2 = (const float*)d_in[6];
    const float* We1 = (const float*)d_in[7];
    const float* be1 = (const float*)d_in[8];
    const float* We2 = (const float*)d_in[9];
    const float* be2 = (const float*)d_in[10];
    const float* eps = (const float*)d_in[11];
    float* out = (float*)d_out;

    float* ws = (float*)d_ws;
    float* agg    = ws;                 // N*C*F          = 262144 f
    float* adense = ws + 262144;        // N*N*C          = 4194304 f
    float* hid    = ws + 4456448;       // N*H            = 262144 f
    float* xn     = ws + 4718592;       // N*F            = 65536 f
    float* Pb     = ws + 4784128;       // N*H            = 262144 f
    float* Qb     = ws + 5046272;       // N*H            = 262144 f
    // total 5308416 floats = 21.2 MB of workspace

    // zero the two scatter targets (ws is poisoned 0xAA before every launch)
    hipMemsetAsync(d_ws, 0, (size_t)(262144 + 4194304) * sizeof(float), stream);

    k_agg_scatter<<<(CC * EE * FF) / 256, 256, 0, stream>>>(x, ei, ew, agg);
    k_adj_scatter<<<(CC * EE) / 256, 256, 0, stream>>>(ei, ew, adense);
    k_node_mlp1<<<NN / 4, 256, 0, stream>>>(agg, x, Wn1, bn1, eps, hid);
    k_node_mlp2<<<NN / 4, 256, 0, stream>>>(hid, Wn2, bn2, xn);
    k_pq<<<NN / 4, 256, 0, stream>>>(xn, We1, be1, Pb, Qb);

    dim3 g(NN / 64, NN / 64);
    k_edge_mlp<<<g, 256, 0, stream>>>(Pb, Qb, adense, We1, We2, be2, out);
}